// Round 10
// baseline (125.169 us; speedup 1.0000x reference)
//
#include <hip/hip_runtime.h>

// Decimate-by-4, 129-tap windowed-sinc (polyphase, float4-chunk LDS layout).
// y[r,m] = sum_{j=0..128} k[j] * x_ext[r, 4m + j - 64]
//   x_ext: reflect left, zero past T (max touched idx 1048639 < zero-pad end).
//
// Round-5 structure: persistent blocks (4 consecutive tiles each) with
// double-buffered LDS and the T3 minimum 2-phase pipeline:
//   STAGE(next tile -> buf^1); compute(buf); __syncthreads(); swap.
// The prefetch is in flight across the whole compute phase, so the barrier's
// implicit vmcnt(0) drain is cheap and VMEM stays continuously busy.
// Chunk swizzle q ^= (q>>3)&0x70 (involution, 128B-aligned-safe): linear LDS
// dest for global_load_lds + pre-swizzled GLOBAL source + swizzled read
// (both-sides rule m173/m104). Balanced b128 reads: 8 lanes/granule.

#define T_LEN 1048576
#define OUT_PER_ROW (T_LEN / 4)                       // 262144
#define C 8                                           // outputs per thread
#define BLOCK 256
#define OUT_PER_TILE (BLOCK * C)                      // 2048
#define TILES_PER_ROW (OUT_PER_ROW / OUT_PER_TILE)    // 128
#define NCHUNK (OUT_PER_TILE + 32)                    // 2080 float4 chunks
#define BUF_BYTES (NCHUNK * 16)                       // 33280 (= 260*128)
#define TPB 4                                         // tiles per block

__device__ __forceinline__ unsigned swz(unsigned q) {
  return q ^ ((q >> 3) & 0x70u);                      // bits[6:4] ^= bits[9:7]
}

__device__ __forceinline__ void gload_lds16(const void* g, void* l) {
  __builtin_amdgcn_global_load_lds(
      (const __attribute__((address_space(1))) void*)g,
      (__attribute__((address_space(3))) void*)l, 16, 0, 0);
}

__device__ __forceinline__ void stage_tile(const float* __restrict__ x,
                                           int gt, char* s_buf, int tid) {
  const int row = gt >> 7;                            // / TILES_PER_ROW
  const int blk = gt & (TILES_PER_ROW - 1);
  const float* xr = x + (size_t)row * T_LEN;
  const int win0 = 4 * blk * OUT_PER_TILE - 64;

  if (blk != 0 && blk != TILES_PER_ROW - 1) {
    const char* gb = (const char*)(xr + win0);
    #pragma unroll
    for (int g = 0; g < 8; ++g) {
      unsigned lq = (unsigned)(g * BLOCK + tid) * 16u;
      gload_lds16(gb + swz(lq), s_buf + lq);
    }
    if (tid < NCHUNK - 8 * BLOCK) {                   // 32 remainder chunks
      unsigned lq = (unsigned)(8 * BLOCK + tid) * 16u;
      gload_lds16(gb + swz(lq), s_buf + lq);
    }
  } else {
    for (int i = tid; i < NCHUNK; i += BLOCK) {
      unsigned lq = (unsigned)i * 16u;
      float v[4];
      #pragma unroll
      for (int p = 0; p < 4; ++p) {
        int g = win0 + 4 * i + p;
        float t = 0.0f;
        if (g < 0) t = xr[-g];
        else if (g < T_LEN) t = xr[g];
        v[p] = t;
      }
      *(float4*)(s_buf + swz(lq)) = make_float4(v[0], v[1], v[2], v[3]);
    }
  }
}

__device__ __forceinline__ void compute_tile(const float* __restrict__ kk,
                                             float* __restrict__ out, int gt,
                                             const char* s_buf, int tid) {
  const int row = gt >> 7;
  const int blk = gt & (TILES_PER_ROW - 1);
  const int m0 = tid * C;

  float acc[C];
  #pragma unroll
  for (int i = 0; i < C; ++i) acc[i] = 0.0f;

  const unsigned qb = (unsigned)m0 * 16u;
  // Chunk n feeds output c with tap group e = n-c in [0,32]; j = 4e+p
  // (e == 32 valid only for p == 0, i.e. k[128]).
  #pragma unroll
  for (int n = 0; n < 40; ++n) {
    unsigned q = qb + (unsigned)n * 16u;
    const float4 w = *(const float4*)(s_buf + swz(q));
    #pragma unroll
    for (int c = 0; c < C; ++c) {
      const int e = n - c;
      if (e < 0 || e > 32) continue;                  // compile-time pruned
      if (e == 32) {
        acc[c] = fmaf(kk[128], w.x, acc[c]);
      } else {
        acc[c] = fmaf(kk[4 * e + 0], w.x, acc[c]);
        acc[c] = fmaf(kk[4 * e + 1], w.y, acc[c]);
        acc[c] = fmaf(kk[4 * e + 2], w.z, acc[c]);
        acc[c] = fmaf(kk[4 * e + 3], w.w, acc[c]);
      }
    }
  }

  float* op = out + (size_t)row * OUT_PER_ROW + blk * OUT_PER_TILE + m0;
  *(float4*)(op)     = make_float4(acc[0], acc[1], acc[2], acc[3]);
  *(float4*)(op + 4) = make_float4(acc[4], acc[5], acc[6], acc[7]);
}

__global__ __launch_bounds__(BLOCK, 2) void decim_kernel(
    const float* __restrict__ x, const float* __restrict__ kk,
    float* __restrict__ out) {
  __shared__ __align__(128) char s_mem[2 * BUF_BYTES];  // 66560 B -> 2 blk/CU

  const int tid = threadIdx.x;
  const int t0 = blockIdx.x * TPB;                    // 4 consecutive tiles

  stage_tile(x, t0, s_mem, tid);                      // prologue
  __syncthreads();                                    // vmcnt(0) drain

  int cur = 0;
  #pragma unroll 1
  for (int t = 0; t < TPB; ++t) {
    if (t + 1 < TPB)
      stage_tile(x, t0 + t + 1, s_mem + (cur ^ 1) * BUF_BYTES, tid);
    compute_tile(kk, out, t0 + t, s_mem + cur * BUF_BYTES, tid);
    __syncthreads();                                  // drains prefetch issued above
    cur ^= 1;
  }
}

extern "C" void kernel_launch(void* const* d_in, const int* in_sizes, int n_in,
                              void* d_out, int out_size, void* d_ws, size_t ws_size,
                              hipStream_t stream) {
  const float* x = (const float*)d_in[0];
  const float* k = (const float*)d_in[1];
  float* out = (float*)d_out;
  const int rows = in_sizes[0] / T_LEN;               // 16
  dim3 grid(rows * TILES_PER_ROW / TPB);              // 512 persistent blocks
  decim_kernel<<<grid, BLOCK, 0, stream>>>(x, k, out);
}